// Round 25
// baseline (92.807 us; speedup 1.0000x reference)
//
#include <hip/hip_runtime.h>
#include <hip/hip_bf16.h>
#include <stdint.h>

// Problem constants (fixed by the reference)
#define P 2048       // D_STATE
#define HN 64        // D_INPUT
#define L 16384      // kernel_size
#define BN 64        // l-columns per block (2 n-tiles of 32)

typedef __bf16 bf16_t;
typedef bf16_t bf16x8 __attribute__((ext_vector_type(8)));
typedef float f32x16 __attribute__((ext_vector_type(16)));

__device__ __forceinline__ float2 cmul(float2 a, float2 b) {
    return make_float2(a.x * b.x - a.y * b.y, a.x * b.y + a.y * b.x);
}

__device__ __forceinline__ uint32_t packbf(float2 v) {
    union { __hip_bfloat162 v; uint32_t u; } cv;
    cv.v = __float22bfloat162_rn(make_float2(v.x, v.y));
    return cv.u;
}

// ---------------------------------------------------------------------------
// Prep 1 (grid 128 x 256): block-invariant tables (unchanged from R24).
// (a) wexp: W in bf16 32x32-MFMA A-fragment order.
// (b) Tcol[p*32 + lc] = A_p^lc, lc in [0,32).
__global__ void mv_prep1(const float* __restrict__ Win,
                         const float* __restrict__ Ain,
                         uint4* __restrict__ wexp,
                         float2* __restrict__ tcol) {
    int gid = blockIdx.x * 256 + threadIdx.x;   // 32768
    {   // (a) wexp
        int lane = gid & 63;
        int mt = (gid >> 6) & 1;
        int q = (gid >> 7) & 1;
        int kt = gid >> 8;
        int m = mt * 32 + (lane & 31);
        int p0 = kt * 16 + q * 8 + (lane >> 5) * 4;
        const float4* wp = (const float4*)(Win + (size_t)(m * P + p0) * 2);
        float4 f0 = wp[0], f1 = wp[1];
        float re[4] = {f0.x, f0.z, f1.x, f1.z};
        float im[4] = {f0.y, f0.w, f1.y, f1.w};
        uint32_t o[4];
#pragma unroll
        for (int j = 0; j < 4; ++j)
            o[j] = packbf(make_float2(re[j], -im[j]));
        wexp[gid] = make_uint4(o[0], o[1], o[2], o[3]);
    }
    {   // (b) Tcol
        int p = gid >> 4;
        int e = gid & 15;
        float2 a = *(const float2*)(Ain + 2 * p);
        float2 a2 = cmul(a, a);
        float2 r = make_float2(1.f, 0.f);
        float2 sq = a2;
#pragma unroll
        for (int b = 0; b < 4; ++b) {
            if ((e >> b) & 1) r = cmul(r, sq);
            sq = cmul(sq, sq);
        }
        tcol[(size_t)p * 32 + 2 * e] = r;
        tcol[(size_t)p * 32 + 2 * e + 1] = cmul(r, a);
    }
}

// ---------------------------------------------------------------------------
// Prep 2 (1M threads): TB[j*P + p] = A_p^(32*j), j in [0,512). (unchanged)
__global__ void mv_prep2(const float* __restrict__ Ain,
                         float2* __restrict__ tb) {
    int gid = blockIdx.x * 256 + threadIdx.x;   // 1048576
    int p = gid & (P - 1);
    int j = gid >> 11;                           // [0,512)
    float2 a = *(const float2*)(Ain + 2 * p);
    float2 a32 = a;
#pragma unroll
    for (int s = 0; s < 5; ++s) a32 = cmul(a32, a32);   // A^32
    float2 r = make_float2(1.f, 0.f);
    float2 sq = a32;
#pragma unroll
    for (int b = 0; b < 9; ++b) {
        if ((j >> b) & 1) r = cmul(r, sq);
        sq = cmul(sq, sq);
    }
    tb[(size_t)j * P + p] = r;                           // A^(32*j)
}

// ---------------------------------------------------------------------------
// Main: grid 256 x 512 thr (8 waves). Wave w: kt in [16w,16w+16) (split-K),
// 2 m-tiles x 2 n-tiles (BN=64) with 32x32x16 MFMA. Second n-tile reuses the
// SAME Tcol values with Base1 = A^(32*(2bn)+32) — so per-kt VMEM is identical
// to the BN=32 version while feeding 2x the MFMAs (wexp traffic halved).
// LDS: Base0/Base1 (32 KB) aliased as the 64 KB Red buffer after the K-loop.
__global__ void __launch_bounds__(512, 4) mv_main(
    const uint4* __restrict__ wexp,
    const float2* __restrict__ Tcol,
    const float2* __restrict__ TB,
    float* __restrict__ out) {
    __shared__ __align__(16) float smem[16384];   // 64 KB

    const int t = threadIdx.x;      // 0..511
    const int bn = blockIdx.x;      // 0..255
    const int w = t >> 6;           // wave 0..7
    const int lw = t & 63;

    float2* Base0 = (float2*)smem;          // [0, 2048)
    float2* Base1 = ((float2*)smem) + P;    // [2048, 4096)

    {   // Base0 <- TB[2bn], Base1 <- TB[2bn+1] (32 KB coalesced)
        const float4* s0 = (const float4*)(TB + (size_t)(2 * bn) * P);
        const float4* s1 = (const float4*)(TB + (size_t)(2 * bn + 1) * P);
        float4* d0 = (float4*)Base0;
        float4* d1 = (float4*)Base1;
        d0[t] = s0[t];
        d0[512 + t] = s0[512 + t];
        d1[t] = s1[t];
        d1[512 + t] = s1[512 + t];
    }
    __syncthreads();

    const int n = lw & 31;
    const int kh = lw >> 5;

    f32x16 acc[2][2];   // [mt][nt]
#pragma unroll
    for (int i = 0; i < 2; ++i)
#pragma unroll
        for (int j = 0; j < 2; ++j)
#pragma unroll
            for (int r = 0; r < 16; ++r) acc[i][j][r] = 0.f;

    const int kt0 = w * 16;
    const uint4* wq = wexp + (size_t)kt0 * 256 + lw;
    const float2* tq = Tcol + (size_t)kt0 * 512 + kh * 128 + n;
    const float4* bb0 = ((const float4*)Base0) + kt0 * 8 + kh * 2;
    const float4* bb1 = ((const float4*)Base1) + kt0 * 8 + kh * 2;

    for (int kt = 0; kt < 16; ++kt) {
        uint4 a00 = wq[0];     // mt0 q0
        uint4 a10 = wq[64];    // mt1 q0
        uint4 a01 = wq[128];   // mt0 q1
        uint4 a11 = wq[192];   // mt1 q1
        float2 t0 = tq[0],   t1 = tq[32],  t2 = tq[64],  t3 = tq[96];
        float2 t4 = tq[256], t5 = tq[288], t6 = tq[320], t7 = tq[352];
#pragma unroll
        for (int q = 0; q < 2; ++q) {
            float4 c0 = bb0[q * 4], c1 = bb0[q * 4 + 1];
            float4 d0 = bb1[q * 4], d1 = bb1[q * 4 + 1];
            float2 u0 = q ? t4 : t0, u1 = q ? t5 : t1;
            float2 u2 = q ? t6 : t2, u3 = q ? t7 : t3;
            union { uint4 u; bf16x8 b; } f0, f1, am0, am1;
            f0.u = make_uint4(packbf(cmul(make_float2(c0.x, c0.y), u0)),
                              packbf(cmul(make_float2(c0.z, c0.w), u1)),
                              packbf(cmul(make_float2(c1.x, c1.y), u2)),
                              packbf(cmul(make_float2(c1.z, c1.w), u3)));
            f1.u = make_uint4(packbf(cmul(make_float2(d0.x, d0.y), u0)),
                              packbf(cmul(make_float2(d0.z, d0.w), u1)),
                              packbf(cmul(make_float2(d1.x, d1.y), u2)),
                              packbf(cmul(make_float2(d1.z, d1.w), u3)));
            am0.u = q ? a01 : a00;
            am1.u = q ? a11 : a10;
            acc[0][0] = __builtin_amdgcn_mfma_f32_32x32x16_bf16(am0.b, f0.b, acc[0][0], 0, 0, 0);
            acc[1][0] = __builtin_amdgcn_mfma_f32_32x32x16_bf16(am1.b, f0.b, acc[1][0], 0, 0, 0);
            acc[0][1] = __builtin_amdgcn_mfma_f32_32x32x16_bf16(am0.b, f1.b, acc[0][1], 0, 0, 0);
            acc[1][1] = __builtin_amdgcn_mfma_f32_32x32x16_bf16(am1.b, f1.b, acc[1][1], 0, 0, 0);
        }
        wq += 256; tq += 512; bb0 += 8; bb1 += 8;
    }

    __syncthreads();   // all waves done reading Base0/Base1 -> reuse as Red
    float* Red = smem; // [4][4096]

    if (w < 4) {
#pragma unroll
        for (int mt = 0; mt < 2; ++mt)
#pragma unroll
            for (int nt = 0; nt < 2; ++nt)
#pragma unroll
                for (int r = 0; r < 16; ++r)
                    Red[w * 4096 + (mt * 2 + nt) * 1024 + r * 64 + lw] = acc[mt][nt][r];
    }
    __syncthreads();
    if (w >= 4) {
#pragma unroll
        for (int mt = 0; mt < 2; ++mt)
#pragma unroll
            for (int nt = 0; nt < 2; ++nt)
#pragma unroll
                for (int r = 0; r < 16; ++r)
                    Red[(w - 4) * 4096 + (mt * 2 + nt) * 1024 + r * 64 + lw] += acc[mt][nt][r];
    }
    __syncthreads();

    // C/D layout (m74): col = lane&31, row = (r&3) + 8*(r>>2) + 4*(lane>>5)
#pragma unroll
    for (int i = 0; i < 8; ++i) {
        int idx = i * 512 + t;                       // 0..4095
        float s = Red[idx] + Red[4096 + idx] + Red[8192 + idx] + Red[12288 + idx];
        int lane = idx & 63;
        int r = (idx >> 6) & 15;
        int tile = idx >> 10;
        int mt = tile >> 1, nt = tile & 1;
        int row = (r & 3) + 8 * (r >> 2) + 4 * (lane >> 5);
        int hh = mt * 32 + row;
        int ll = bn * BN + nt * 32 + (lane & 31);
        out[(size_t)hh * L + ll] = s;
    }
}

// ---------------------------------------------------------------------------
extern "C" void kernel_launch(void* const* d_in, const int* in_sizes, int n_in,
                              void* d_out, int out_size, void* d_ws, size_t ws_size,
                              hipStream_t stream) {
    const float* Ain = nullptr;
    const float* Win = nullptr;
    for (int i = 0; i < n_in; ++i) {
        if (in_sizes[i] == 2 * P) Ain = (const float*)d_in[i];
        else if (in_sizes[i] == 2 * HN * P) Win = (const float*)d_in[i];
    }
    if (!Ain) Ain = (const float*)d_in[0];
    if (!Win) Win = (const float*)d_in[1];
    (void)out_size; (void)ws_size;                          // ws = 256 MB (measured R20)
    uint4* wexp = (uint4*)d_ws;                             // 512 KB
    float2* tcol = (float2*)((char*)d_ws + 512 * 1024);     // +512 KB
    float2* tb = (float2*)((char*)d_ws + 1024 * 1024);      // +8 MB
    mv_prep1<<<128, 256, 0, stream>>>(Win, Ain, wexp, tcol);
    mv_prep2<<<4096, 256, 0, stream>>>(Ain, tb);
    mv_main<<<L / BN, 512, 0, stream>>>(wexp, tcol, tb, (float*)d_out);
}

// Round 26
// 91.925 us; speedup vs baseline: 1.0096x; 1.0096x over previous
//
#include <hip/hip_runtime.h>
#include <hip/hip_bf16.h>
#include <stdint.h>

// Problem constants (fixed by the reference)
#define P 2048       // D_STATE
#define HN 64        // D_INPUT
#define L 16384      // kernel_size
#define BN 32        // l-columns per block

typedef __bf16 bf16_t;
typedef bf16_t bf16x8 __attribute__((ext_vector_type(8)));
typedef float f32x16 __attribute__((ext_vector_type(16)));

__device__ __forceinline__ float2 cmul(float2 a, float2 b) {
    return make_float2(a.x * b.x - a.y * b.y, a.x * b.y + a.y * b.x);
}

__device__ __forceinline__ uint32_t packbf(float2 v) {
    union { __hip_bfloat162 v; uint32_t u; } cv;
    cv.v = __float22bfloat162_rn(make_float2(v.x, v.y));
    return cv.u;
}

// ---------------------------------------------------------------------------
// Prep 1 (grid 128 x 256): block-invariant tables (unchanged).
// (a) wexp: W in bf16 32x32-MFMA A-fragment order.
// (b) Tcol[p*32 + lc] = A_p^lc, lc in [0,32).
__global__ void mv_prep1(const float* __restrict__ Win,
                         const float* __restrict__ Ain,
                         uint4* __restrict__ wexp,
                         float2* __restrict__ tcol) {
    int gid = blockIdx.x * 256 + threadIdx.x;   // 32768
    {   // (a) wexp
        int lane = gid & 63;
        int mt = (gid >> 6) & 1;
        int q = (gid >> 7) & 1;
        int kt = gid >> 8;
        int m = mt * 32 + (lane & 31);
        int p0 = kt * 16 + q * 8 + (lane >> 5) * 4;
        const float4* wp = (const float4*)(Win + (size_t)(m * P + p0) * 2);
        float4 f0 = wp[0], f1 = wp[1];
        float re[4] = {f0.x, f0.z, f1.x, f1.z};
        float im[4] = {f0.y, f0.w, f1.y, f1.w};
        uint32_t o[4];
#pragma unroll
        for (int j = 0; j < 4; ++j)
            o[j] = packbf(make_float2(re[j], -im[j]));
        wexp[gid] = make_uint4(o[0], o[1], o[2], o[3]);
    }
    {   // (b) Tcol
        int p = gid >> 4;
        int e = gid & 15;
        float2 a = *(const float2*)(Ain + 2 * p);
        float2 a2 = cmul(a, a);
        float2 r = make_float2(1.f, 0.f);
        float2 sq = a2;
#pragma unroll
        for (int b = 0; b < 4; ++b) {
            if ((e >> b) & 1) r = cmul(r, sq);
            sq = cmul(sq, sq);
        }
        tcol[(size_t)p * 32 + 2 * e] = r;
        tcol[(size_t)p * 32 + 2 * e + 1] = cmul(r, a);
    }
}

// ---------------------------------------------------------------------------
// Prep 2 (1M threads): TB[j*P + p] = A_p^(32*j), j in [0,512). (unchanged)
__global__ void mv_prep2(const float* __restrict__ Ain,
                         float2* __restrict__ tb) {
    int gid = blockIdx.x * 256 + threadIdx.x;   // 1048576
    int p = gid & (P - 1);
    int j = gid >> 11;                           // [0,512)
    float2 a = *(const float2*)(Ain + 2 * p);
    float2 a32 = a;
#pragma unroll
    for (int s = 0; s < 5; ++s) a32 = cmul(a32, a32);   // A^32
    float2 r = make_float2(1.f, 0.f);
    float2 sq = a32;
#pragma unroll
    for (int b = 0; b < 9; ++b) {
        if ((j >> b) & 1) r = cmul(r, sq);
        sq = cmul(sq, sq);
    }
    tb[(size_t)j * P + p] = r;                           // A^(32*j)
}

// ---------------------------------------------------------------------------
// Main: grid 512 x 512 thr (8 waves), BN=32, split-K 8 ways, 32x32x16 MFMA,
// B generated in-register (Base x Tcol). R26 change: TWO-LEVEL ACCESS SKEW —
// (1) wave->kt-range permuted per block: kt0 = ((w+bn)&7)*16;
// (2) kt-phase rotated per block: kt = kt0 + ((i+bn)&15).
// All 512 blocks previously walked identical table addresses in lockstep ->
// same-line L2 bank serialization (the ~40 us plateau, R21-R25). The skew
// decorrelates streams; bytes/instructions are unchanged.
__global__ void __launch_bounds__(512, 4) mv_main(
    const uint4* __restrict__ wexp,
    const float2* __restrict__ Tcol,
    const float2* __restrict__ TB,
    float* __restrict__ out) {
    __shared__ __align__(16) float2 Base[P];   // 16 KB: A_p^(32*bn)
    __shared__ float Red[4][2048];             // 32 KB: staged partials

    const int t = threadIdx.x;      // 0..511
    const int bn = blockIdx.x;
    const int w = t >> 6;           // wave 0..7
    const int lw = t & 63;

    {   // Base <- TB[bn] (16 KB coalesced)
        const float4* src = (const float4*)(TB + (size_t)bn * P);
        float4* dst = (float4*)Base;
        dst[t] = src[t];
        dst[512 + t] = src[512 + t];
    }
    __syncthreads();

    const int n = lw & 31;
    const int kh = lw >> 5;

    f32x16 acc0, acc1;
#pragma unroll
    for (int r = 0; r < 16; ++r) { acc0[r] = 0.f; acc1[r] = 0.f; }

    const int kt0 = ((w + bn) & 7) * 16;   // wave->range permutation
    const int rot = bn & 15;               // phase rotation
    const float4* Bf4 = (const float4*)Base;

#pragma unroll 2
    for (int i = 0; i < 16; ++i) {
        int kt = kt0 + ((i + rot) & 15);
        const uint4* wq = wexp + ((size_t)kt << 8) + lw;
        const float2* tq = Tcol + ((size_t)kt << 9) + kh * 128 + n;
        const float4* bb = Bf4 + (kt << 3) + (kh << 1);
        // all independent loads up front (compiler batches vmcnt)
        uint4 a00 = wq[0];     // mt0 q0
        uint4 a10 = wq[64];    // mt1 q0
        uint4 a01 = wq[128];   // mt0 q1
        uint4 a11 = wq[192];   // mt1 q1
        float2 t0 = tq[0],   t1 = tq[32],  t2 = tq[64],  t3 = tq[96];
        float2 t4 = tq[256], t5 = tq[288], t6 = tq[320], t7 = tq[352];
        float4 b0 = bb[0], b1 = bb[1], b2 = bb[4], b3 = bb[5];
        {   // q = 0
            uint32_t f0 = packbf(cmul(make_float2(b0.x, b0.y), t0));
            uint32_t f1 = packbf(cmul(make_float2(b0.z, b0.w), t1));
            uint32_t f2 = packbf(cmul(make_float2(b1.x, b1.y), t2));
            uint32_t f3 = packbf(cmul(make_float2(b1.z, b1.w), t3));
            union { uint4 u; bf16x8 b; } bf, am0, am1;
            bf.u = make_uint4(f0, f1, f2, f3);
            am0.u = a00; am1.u = a10;
            acc0 = __builtin_amdgcn_mfma_f32_32x32x16_bf16(am0.b, bf.b, acc0, 0, 0, 0);
            acc1 = __builtin_amdgcn_mfma_f32_32x32x16_bf16(am1.b, bf.b, acc1, 0, 0, 0);
        }
        {   // q = 1
            uint32_t f0 = packbf(cmul(make_float2(b2.x, b2.y), t4));
            uint32_t f1 = packbf(cmul(make_float2(b2.z, b2.w), t5));
            uint32_t f2 = packbf(cmul(make_float2(b3.x, b3.y), t6));
            uint32_t f3 = packbf(cmul(make_float2(b3.z, b3.w), t7));
            union { uint4 u; bf16x8 b; } bf, am0, am1;
            bf.u = make_uint4(f0, f1, f2, f3);
            am0.u = a01; am1.u = a11;
            acc0 = __builtin_amdgcn_mfma_f32_32x32x16_bf16(am0.b, bf.b, acc0, 0, 0, 0);
            acc1 = __builtin_amdgcn_mfma_f32_32x32x16_bf16(am1.b, bf.b, acc1, 0, 0, 0);
        }
    }

    // ---- staged cross-wave reduction (split-K over 8 waves) ----
    if (w < 4) {
#pragma unroll
        for (int r = 0; r < 16; ++r) {
            Red[w][r * 64 + lw] = acc0[r];
            Red[w][(16 + r) * 64 + lw] = acc1[r];
        }
    }
    __syncthreads();
    if (w >= 4) {
#pragma unroll
        for (int r = 0; r < 16; ++r) {
            Red[w - 4][r * 64 + lw] += acc0[r];
            Red[w - 4][(16 + r) * 64 + lw] += acc1[r];
        }
    }
    __syncthreads();

    // C/D layout (m74): col = lane&31, row = (r&3) + 8*(r>>2) + 4*(lane>>5)
#pragma unroll
    for (int i = 0; i < 4; ++i) {
        int idx = i * 512 + t;
        float s = Red[0][idx] + Red[1][idx] + Red[2][idx] + Red[3][idx];
        int lane = idx & 63;
        int r = (idx >> 6) & 15;
        int mt = idx >> 10;
        int row = (r & 3) + 8 * (r >> 2) + 4 * (lane >> 5);
        int hh = mt * 32 + row;
        int ll = bn * BN + (lane & 31);
        out[(size_t)hh * L + ll] = s;
    }
}

// ---------------------------------------------------------------------------
extern "C" void kernel_launch(void* const* d_in, const int* in_sizes, int n_in,
                              void* d_out, int out_size, void* d_ws, size_t ws_size,
                              hipStream_t stream) {
    const float* Ain = nullptr;
    const float* Win = nullptr;
    for (int i = 0; i < n_in; ++i) {
        if (in_sizes[i] == 2 * P) Ain = (const float*)d_in[i];
        else if (in_sizes[i] == 2 * HN * P) Win = (const float*)d_in[i];
    }
    if (!Ain) Ain = (const float*)d_in[0];
    if (!Win) Win = (const float*)d_in[1];
    (void)out_size; (void)ws_size;                          // ws = 256 MB (measured R20)
    uint4* wexp = (uint4*)d_ws;                             // 512 KB
    float2* tcol = (float2*)((char*)d_ws + 512 * 1024);     // +512 KB
    float2* tb = (float2*)((char*)d_ws + 1024 * 1024);      // +8 MB
    mv_prep1<<<128, 256, 0, stream>>>(Win, Ain, wexp, tcol);
    mv_prep2<<<4096, 256, 0, stream>>>(Ain, tb);
    mv_main<<<L / BN, 512, 0, stream>>>(wexp, tcol, tb, (float*)d_out);
}